// Round 5
// baseline (286.819 us; speedup 1.0000x reference)
//
#include <hip/hip_runtime.h>

#define N_NODES 50000
#define N_EDGES 800000
#define D_FEAT 64
#define SCAN_THREADS 1024

// ---------------- CSR build ----------------

__global__ void hist_kernel(const int* __restrict__ dst, int* __restrict__ cnt) {
    int e = blockIdx.x * blockDim.x + threadIdx.x;
    if (e < N_EDGES) atomicAdd(&cnt[dst[e]], 1);
}

// Single-block exclusive scan of cnt[0..N_NODES) -> offsets/cursor.
// Each of 1024 threads serially handles a contiguous 49-element chunk;
// chunk sums are scanned wave-wise (shfl_up) + 16-entry LDS for wave bases.
__global__ void scan_fused_kernel(const int* __restrict__ cnt,
                                  int* __restrict__ offsets,
                                  int* __restrict__ cursor) {
    __shared__ int wavesum[SCAN_THREADS / 64];  // 16
    int t = threadIdx.x;
    const int CHUNK = (N_NODES + SCAN_THREADS - 1) / SCAN_THREADS;  // 49
    int beg = t * CHUNK;
    int end = beg + CHUNK;
    if (beg > N_NODES) beg = N_NODES;
    if (end > N_NODES) end = N_NODES;

    int local = 0;
    for (int i = beg; i < end; ++i) local += cnt[i];

    // Inclusive scan of `local` across the 64-lane wave.
    int lane = t & 63;
    int wave = t >> 6;
    int incl = local;
    #pragma unroll
    for (int off = 1; off < 64; off <<= 1) {
        int x = __shfl_up(incl, off);
        if (lane >= off) incl += x;
    }
    if (lane == 63) wavesum[wave] = incl;
    __syncthreads();

    int wbase = 0;
    #pragma unroll
    for (int w = 0; w < SCAN_THREADS / 64; ++w)
        wbase += (w < wave) ? wavesum[w] : 0;

    int run = wbase + incl - local;  // exclusive prefix for this chunk
    for (int i = beg; i < end; ++i) {
        offsets[i] = run;
        cursor[i] = run;
        run += cnt[i];
    }
    if (beg < N_NODES && end == N_NODES) offsets[N_NODES] = run;
}

__global__ void scatter_ids_kernel(const int* __restrict__ src, const int* __restrict__ dst,
                                   int* __restrict__ cursor, int* __restrict__ esrc) {
    int e = blockIdx.x * blockDim.x + threadIdx.x;
    if (e >= N_EDGES) return;
    int pos = atomicAdd(&cursor[dst[e]], 1);
    esrc[pos] = src[e];
}

// ---------------- Pull (atomic-free accumulate) ----------------
// 16 threads per node, one float4 per thread. Edge ids loaded cooperatively
// (16 at a time, coalesced, nontemporal) and broadcast via __shfl within the
// group. Output stores are nontemporal so the 12.8 MB `out` stream does not
// evict the random-gathered `xs` (12.8 MB, ~16x reuse) from L2.
__global__ void pull_kernel(const float* __restrict__ xs,
                            const int* __restrict__ esrc,
                            const int* __restrict__ offsets,
                            float* __restrict__ out) {
    int tid = blockIdx.x * blockDim.x + threadIdx.x;
    int node = tid >> 4;
    int c = tid & 15;
    if (node >= N_NODES) return;
    int beg = offsets[node];
    int end = offsets[node + 1];
    int deg = end - beg;
    float4 acc = make_float4(0.f, 0.f, 0.f, 0.f);
    for (int j0 = 0; j0 < deg; j0 += 16) {
        int rem = deg - j0;
        int m = rem < 16 ? rem : 16;
        int myid = (c < m) ? __builtin_nontemporal_load(esrc + beg + j0 + c) : 0;
        if (m == 16) {
            #pragma unroll
            for (int k = 0; k < 16; ++k) {
                int s = __shfl(myid, k, 16);
                const float4 v = *reinterpret_cast<const float4*>(xs + s * D_FEAT + c * 4);
                acc.x += v.x; acc.y += v.y; acc.z += v.z; acc.w += v.w;
            }
        } else {
            for (int k = 0; k < m; ++k) {
                int s = __shfl(myid, k, 16);
                const float4 v = *reinterpret_cast<const float4*>(xs + s * D_FEAT + c * 4);
                acc.x += v.x; acc.y += v.y; acc.z += v.z; acc.w += v.w;
            }
        }
    }
    float inv = 1.0f / fmaxf((float)deg, 1.0f);
    float* op = out + node * D_FEAT + c * 4;
    __builtin_nontemporal_store(acc.x * inv, op + 0);
    __builtin_nontemporal_store(acc.y * inv, op + 1);
    __builtin_nontemporal_store(acc.z * inv, op + 2);
    __builtin_nontemporal_store(acc.w * inv, op + 3);
}

// ---------------- Fallback (small ws): baseline atomic push ----------------

__global__ void scatter_kernel(const float* __restrict__ xs,
                               const int* __restrict__ src,
                               const int* __restrict__ dst,
                               float* __restrict__ sums,
                               float* __restrict__ counts) {
    int tid = blockIdx.x * blockDim.x + threadIdx.x;
    int e = tid >> 4;
    int c = tid & 15;
    if (e >= N_EDGES) return;
    int s = src[e];
    int d = dst[e];
    const float4 v = *reinterpret_cast<const float4*>(xs + (size_t)s * D_FEAT + c * 4);
    float* outp = sums + (size_t)d * D_FEAT + c * 4;
    atomicAdd(outp + 0, v.x);
    atomicAdd(outp + 1, v.y);
    atomicAdd(outp + 2, v.z);
    atomicAdd(outp + 3, v.w);
    if (c == 0) atomicAdd(counts + d, 1.0f);
}

__global__ void divide_kernel(float* __restrict__ out, const float* __restrict__ counts) {
    int tid = blockIdx.x * blockDim.x + threadIdx.x;
    if (tid >= N_NODES * D_FEAT / 4) return;
    int node = tid >> 4;
    float inv = 1.0f / fmaxf(counts[node], 1.0f);
    float4 v = reinterpret_cast<const float4*>(out)[tid];
    v.x *= inv; v.y *= inv; v.z *= inv; v.w *= inv;
    reinterpret_cast<float4*>(out)[tid] = v;
}

// ---------------- launch ----------------

extern "C" void kernel_launch(void* const* d_in, const int* in_sizes, int n_in,
                              void* d_out, int out_size, void* d_ws, size_t ws_size,
                              hipStream_t stream) {
    const float* xs  = (const float*)d_in[0];
    const int*   src = (const int*)d_in[1];
    const int*   dst = (const int*)d_in[2];
    float* out = (float*)d_out;

    size_t need = (size_t)(N_NODES + (N_NODES + 1) + N_NODES + N_EDGES) * sizeof(int);
    if (ws_size < need) {
        float* counts = (float*)d_ws;
        hipMemsetAsync(out, 0, (size_t)N_NODES * D_FEAT * sizeof(float), stream);
        hipMemsetAsync(counts, 0, (size_t)N_NODES * sizeof(float), stream);
        scatter_kernel<<<(N_EDGES * 16 + 255) / 256, 256, 0, stream>>>(xs, src, dst, out, counts);
        divide_kernel<<<(N_NODES * D_FEAT / 4 + 255) / 256, 256, 0, stream>>>(out, counts);
        return;
    }

    int* ws = (int*)d_ws;
    int* cnt     = ws;                      // N_NODES
    int* offsets = cnt + N_NODES;           // N_NODES + 1
    int* cursor  = offsets + N_NODES + 1;   // N_NODES
    int* esrc    = cursor + N_NODES;        // N_EDGES

    hipMemsetAsync(cnt, 0, (size_t)N_NODES * sizeof(int), stream);

    hist_kernel<<<(N_EDGES + 255) / 256, 256, 0, stream>>>(dst, cnt);
    scan_fused_kernel<<<1, SCAN_THREADS, 0, stream>>>(cnt, offsets, cursor);
    scatter_ids_kernel<<<(N_EDGES + 255) / 256, 256, 0, stream>>>(src, dst, cursor, esrc);
    pull_kernel<<<(N_NODES * 16 + 255) / 256, 256, 0, stream>>>(xs, esrc, offsets, out);
}

// Round 6
// 187.999 us; speedup vs baseline: 1.5256x; 1.5256x over previous
//
#include <hip/hip_runtime.h>

#define N_NODES 50000
#define N_EDGES 800000
#define D_FEAT 64
#define SCAN_BLK 256
#define N_SCAN_BLOCKS ((N_NODES + SCAN_BLK - 1) / SCAN_BLK)  // 196

// ---------------- CSR build ----------------

__global__ void hist_kernel(const int* __restrict__ dst, int* __restrict__ cnt) {
    int e = blockIdx.x * blockDim.x + threadIdx.x;
    if (e < N_EDGES) atomicAdd(&cnt[dst[e]], 1);
}

__global__ void blockreduce_kernel(const int* __restrict__ cnt, int* __restrict__ blocksum) {
    __shared__ int lds[SCAN_BLK];
    int i = blockIdx.x * SCAN_BLK + threadIdx.x;
    lds[threadIdx.x] = (i < N_NODES) ? cnt[i] : 0;
    __syncthreads();
    for (int off = SCAN_BLK / 2; off > 0; off >>= 1) {
        if (threadIdx.x < off) lds[threadIdx.x] += lds[threadIdx.x + off];
        __syncthreads();
    }
    if (threadIdx.x == 0) blocksum[blockIdx.x] = lds[0];
}

// Per-block exclusive scan + base (= sum of preceding block sums).
__global__ void scan_kernel(const int* __restrict__ cnt, const int* __restrict__ blocksum,
                            int* __restrict__ offsets, int* __restrict__ cursor) {
    __shared__ int lds[SCAN_BLK];
    __shared__ int wsum[SCAN_BLK / 64];  // 4 waves
    __shared__ int base_s;
    int b = blockIdx.x, t = threadIdx.x;
    int i = b * SCAN_BLK + t;
    // base = sum(blocksum[0..b)); N_SCAN_BLOCKS (196) <= SCAN_BLK so one pass.
    int part = (t < b) ? blocksum[t] : 0;
    #pragma unroll
    for (int off = 32; off > 0; off >>= 1) part += __shfl_down(part, off);
    if ((t & 63) == 0) wsum[t >> 6] = part;
    __syncthreads();
    if (t == 0) base_s = wsum[0] + wsum[1] + wsum[2] + wsum[3];
    __syncthreads();
    int base = base_s;

    int v = (i < N_NODES) ? cnt[i] : 0;
    lds[t] = v;
    __syncthreads();
    // Hillis-Steele inclusive scan.
    for (int off = 1; off < SCAN_BLK; off <<= 1) {
        int x = (t >= off) ? lds[t - off] : 0;
        __syncthreads();
        lds[t] += x;
        __syncthreads();
    }
    int incl = lds[t];
    int excl = incl - v;
    if (i < N_NODES) { offsets[i] = excl + base; cursor[i] = excl + base; }
    if (i == N_NODES - 1) offsets[N_NODES] = incl + base;
}

__global__ void scatter_ids_kernel(const int* __restrict__ src, const int* __restrict__ dst,
                                   int* __restrict__ cursor, int* __restrict__ esrc) {
    int e = blockIdx.x * blockDim.x + threadIdx.x;
    if (e >= N_EDGES) return;
    int pos = atomicAdd(&cursor[dst[e]], 1);
    esrc[pos] = src[e];
}

// ---------------- Pull (atomic-free accumulate) ----------------
// 16 threads per node, one float4 per thread. Edge ids loaded cooperatively
// (16 at a time, coalesced, nontemporal) and broadcast via __shfl within the
// group. Output stores are nontemporal so the 12.8 MB `out` stream does not
// evict the random-gathered `xs` (12.8 MB, ~16x reuse) from L2.
__global__ void pull_kernel(const float* __restrict__ xs,
                            const int* __restrict__ esrc,
                            const int* __restrict__ offsets,
                            float* __restrict__ out) {
    int tid = blockIdx.x * blockDim.x + threadIdx.x;
    int node = tid >> 4;
    int c = tid & 15;
    if (node >= N_NODES) return;
    int beg = offsets[node];
    int end = offsets[node + 1];
    int deg = end - beg;
    float4 acc = make_float4(0.f, 0.f, 0.f, 0.f);
    for (int j0 = 0; j0 < deg; j0 += 16) {
        int rem = deg - j0;
        int m = rem < 16 ? rem : 16;
        int myid = (c < m) ? __builtin_nontemporal_load(esrc + beg + j0 + c) : 0;
        if (m == 16) {
            #pragma unroll
            for (int k = 0; k < 16; ++k) {
                int s = __shfl(myid, k, 16);
                const float4 v = *reinterpret_cast<const float4*>(xs + s * D_FEAT + c * 4);
                acc.x += v.x; acc.y += v.y; acc.z += v.z; acc.w += v.w;
            }
        } else {
            for (int k = 0; k < m; ++k) {
                int s = __shfl(myid, k, 16);
                const float4 v = *reinterpret_cast<const float4*>(xs + s * D_FEAT + c * 4);
                acc.x += v.x; acc.y += v.y; acc.z += v.z; acc.w += v.w;
            }
        }
    }
    float inv = 1.0f / fmaxf((float)deg, 1.0f);
    float* op = out + node * D_FEAT + c * 4;
    __builtin_nontemporal_store(acc.x * inv, op + 0);
    __builtin_nontemporal_store(acc.y * inv, op + 1);
    __builtin_nontemporal_store(acc.z * inv, op + 2);
    __builtin_nontemporal_store(acc.w * inv, op + 3);
}

// ---------------- Fallback (small ws): baseline atomic push ----------------

__global__ void scatter_kernel(const float* __restrict__ xs,
                               const int* __restrict__ src,
                               const int* __restrict__ dst,
                               float* __restrict__ sums,
                               float* __restrict__ counts) {
    int tid = blockIdx.x * blockDim.x + threadIdx.x;
    int e = tid >> 4;
    int c = tid & 15;
    if (e >= N_EDGES) return;
    int s = src[e];
    int d = dst[e];
    const float4 v = *reinterpret_cast<const float4*>(xs + (size_t)s * D_FEAT + c * 4);
    float* outp = sums + (size_t)d * D_FEAT + c * 4;
    atomicAdd(outp + 0, v.x);
    atomicAdd(outp + 1, v.y);
    atomicAdd(outp + 2, v.z);
    atomicAdd(outp + 3, v.w);
    if (c == 0) atomicAdd(counts + d, 1.0f);
}

__global__ void divide_kernel(float* __restrict__ out, const float* __restrict__ counts) {
    int tid = blockIdx.x * blockDim.x + threadIdx.x;
    if (tid >= N_NODES * D_FEAT / 4) return;
    int node = tid >> 4;
    float inv = 1.0f / fmaxf(counts[node], 1.0f);
    float4 v = reinterpret_cast<const float4*>(out)[tid];
    v.x *= inv; v.y *= inv; v.z *= inv; v.w *= inv;
    reinterpret_cast<float4*>(out)[tid] = v;
}

// ---------------- launch ----------------

extern "C" void kernel_launch(void* const* d_in, const int* in_sizes, int n_in,
                              void* d_out, int out_size, void* d_ws, size_t ws_size,
                              hipStream_t stream) {
    const float* xs  = (const float*)d_in[0];
    const int*   src = (const int*)d_in[1];
    const int*   dst = (const int*)d_in[2];
    float* out = (float*)d_out;

    size_t need = (size_t)(N_NODES + (N_NODES + 1) + N_NODES + N_SCAN_BLOCKS + N_EDGES) * sizeof(int);
    if (ws_size < need) {
        float* counts = (float*)d_ws;
        hipMemsetAsync(out, 0, (size_t)N_NODES * D_FEAT * sizeof(float), stream);
        hipMemsetAsync(counts, 0, (size_t)N_NODES * sizeof(float), stream);
        scatter_kernel<<<(N_EDGES * 16 + 255) / 256, 256, 0, stream>>>(xs, src, dst, out, counts);
        divide_kernel<<<(N_NODES * D_FEAT / 4 + 255) / 256, 256, 0, stream>>>(out, counts);
        return;
    }

    int* ws = (int*)d_ws;
    int* cnt      = ws;                         // N_NODES
    int* offsets  = cnt + N_NODES;              // N_NODES + 1
    int* cursor   = offsets + N_NODES + 1;      // N_NODES
    int* blocksum = cursor + N_NODES;           // N_SCAN_BLOCKS
    int* esrc     = blocksum + N_SCAN_BLOCKS;   // N_EDGES

    hipMemsetAsync(cnt, 0, (size_t)N_NODES * sizeof(int), stream);

    hist_kernel<<<(N_EDGES + 255) / 256, 256, 0, stream>>>(dst, cnt);
    blockreduce_kernel<<<N_SCAN_BLOCKS, SCAN_BLK, 0, stream>>>(cnt, blocksum);
    scan_kernel<<<N_SCAN_BLOCKS, SCAN_BLK, 0, stream>>>(cnt, blocksum, offsets, cursor);
    scatter_ids_kernel<<<(N_EDGES + 255) / 256, 256, 0, stream>>>(src, dst, cursor, esrc);
    pull_kernel<<<(N_NODES * 16 + 255) / 256, 256, 0, stream>>>(xs, esrc, offsets, out);
}

// Round 8
// 184.028 us; speedup vs baseline: 1.5586x; 1.0216x over previous
//
#include <hip/hip_runtime.h>

#define N_NODES 50000
#define N_EDGES 800000
#define D_FEAT 64

#define BIN_SHIFT 6
#define NODES_PER_BIN 64                                   // 1 << BIN_SHIFT
#define NBINS ((N_NODES + NODES_PER_BIN - 1) / NODES_PER_BIN)  // 782
#define NSEG 8
#define NCELL (NBINS * NSEG)                               // 6256
#define LCAP 4096                                          // LDS edge-list capacity (avg bin ~1023)
#define SCAN2_THREADS 1024
#define EDGE_BLOCKS (N_EDGES / 256)                        // 3125 exact

// ---- Pass A: per-(bin, seg) histogram. seg = blockIdx&7 partitions edges by
// issuing block so pass C's sequential claims stay (likely) XCD-local. ----
__global__ void binhist_kernel(const int* __restrict__ dst, int* __restrict__ hist2) {
    int e = blockIdx.x * 256 + threadIdx.x;  // grid exactly covers N_EDGES
    int b = dst[e] >> BIN_SHIFT;
    int seg = blockIdx.x & (NSEG - 1);
    atomicAdd(&hist2[b * NSEG + seg], 1);
}

// ---- Pass B: single-block exclusive scan of hist2[0..NCELL) -> segStart/cursor.
__global__ void binscan_kernel(const int* __restrict__ hist2,
                               int* __restrict__ segStart,
                               int* __restrict__ cursor) {
    __shared__ int wavesum[SCAN2_THREADS / 64];
    int t = threadIdx.x;
    const int CH = (NCELL + SCAN2_THREADS - 1) / SCAN2_THREADS;  // 7
    int beg = t * CH;
    int end = beg + CH;
    if (beg > NCELL) beg = NCELL;
    if (end > NCELL) end = NCELL;

    int local = 0;
    for (int i = beg; i < end; ++i) local += hist2[i];

    int lane = t & 63;
    int wave = t >> 6;
    int incl = local;
    #pragma unroll
    for (int off = 1; off < 64; off <<= 1) {
        int x = __shfl_up(incl, off);
        if (lane >= off) incl += x;
    }
    if (lane == 63) wavesum[wave] = incl;
    __syncthreads();
    int wbase = 0;
    #pragma unroll
    for (int w = 0; w < SCAN2_THREADS / 64; ++w)
        wbase += (w < wave) ? wavesum[w] : 0;

    int run = wbase + incl - local;
    for (int i = beg; i < end; ++i) {
        segStart[i] = run;
        cursor[i] = run;
        run += hist2[i];
    }
    if (t == 0) segStart[NCELL] = N_EDGES;
}

// ---- Pass C: scatter packed (src | dstlow<<16) into staging, sequential per cell.
__global__ void binscatter_kernel(const int* __restrict__ src, const int* __restrict__ dst,
                                  int* __restrict__ cursor, unsigned int* __restrict__ staging) {
    int e = blockIdx.x * 256 + threadIdx.x;
    int d = dst[e];
    int b = d >> BIN_SHIFT;
    int seg = blockIdx.x & (NSEG - 1);
    int pos = atomicAdd(&cursor[b * NSEG + seg], 1);
    unsigned int pk = (unsigned int)src[e] | ((unsigned int)(d & (NODES_PER_BIN - 1)) << 16);
    staging[pos] = pk;
}

// ---- Pass D: fused per-bin counting sort (LDS) + pull + divide + store. ----
__global__ __launch_bounds__(256) void binpull_kernel(const float* __restrict__ xs,
                                                      const unsigned int* __restrict__ staging,
                                                      const int* __restrict__ segStart,
                                                      float* __restrict__ out) {
    __shared__ int cntL[NODES_PER_BIN];
    __shared__ union U {
        struct {
            int off[NODES_PER_BIN + 1];
            int cur[NODES_PER_BIN];
            unsigned short list[LCAP];
        } s;
        float feat[NODES_PER_BIN * D_FEAT];  // 16 KB fallback arena
    } u;

    int bin = blockIdx.x;
    int t = threadIdx.x;
    int lo = segStart[bin * NSEG];
    int hi = segStart[bin * NSEG + NSEG];  // segments are bin-major: contiguous
    int n = hi - lo;
    int nodeLo = bin << BIN_SHIFT;

    if (t < NODES_PER_BIN) cntL[t] = 0;
    __syncthreads();
    for (int i = lo + t; i < hi; i += 256) {
        int dl = (staging[i] >> 16) & (NODES_PER_BIN - 1);
        atomicAdd(&cntL[dl], 1);
    }
    __syncthreads();

    if (n <= LCAP) {
        // exclusive scan of 64 counts in one wave
        if (t < 64) {
            int v = cntL[t];
            int incl = v;
            #pragma unroll
            for (int o = 1; o < 64; o <<= 1) {
                int x = __shfl_up(incl, o);
                if ((t & 63) >= o) incl += x;
            }
            u.s.off[t] = incl - v;
            u.s.cur[t] = incl - v;
            if (t == 63) u.s.off[64] = incl;
        }
        __syncthreads();
        // counting-sort srcs into LDS list
        for (int i = lo + t; i < hi; i += 256) {
            unsigned int pk = staging[i];
            int dl = (pk >> 16) & (NODES_PER_BIN - 1);
            int p = atomicAdd(&u.s.cur[dl], 1);
            u.s.list[p] = (unsigned short)(pk & 0xFFFFu);
        }
        __syncthreads();
        // pull: 16 groups x 16 lanes; lane c owns float4 chunk c
        int g = t >> 4, c = t & 15;
        for (int ng = g; ng < NODES_PER_BIN; ng += 16) {
            int node = nodeLo + ng;
            if (node >= N_NODES) break;
            int beg = u.s.off[ng], end = u.s.off[ng + 1];
            float4 acc = make_float4(0.f, 0.f, 0.f, 0.f);
            int j = beg;
            for (; j + 4 <= end; j += 4) {
                int s0 = u.s.list[j], s1 = u.s.list[j + 1];
                int s2 = u.s.list[j + 2], s3 = u.s.list[j + 3];
                float4 v0 = *reinterpret_cast<const float4*>(xs + s0 * D_FEAT + c * 4);
                float4 v1 = *reinterpret_cast<const float4*>(xs + s1 * D_FEAT + c * 4);
                float4 v2 = *reinterpret_cast<const float4*>(xs + s2 * D_FEAT + c * 4);
                float4 v3 = *reinterpret_cast<const float4*>(xs + s3 * D_FEAT + c * 4);
                acc.x += v0.x + v1.x + v2.x + v3.x;
                acc.y += v0.y + v1.y + v2.y + v3.y;
                acc.z += v0.z + v1.z + v2.z + v3.z;
                acc.w += v0.w + v1.w + v2.w + v3.w;
            }
            for (; j < end; ++j) {
                int s0 = u.s.list[j];
                float4 v0 = *reinterpret_cast<const float4*>(xs + s0 * D_FEAT + c * 4);
                acc.x += v0.x; acc.y += v0.y; acc.z += v0.z; acc.w += v0.w;
            }
            float inv = 1.0f / fmaxf((float)(end - beg), 1.0f);
            float* op = out + (size_t)node * D_FEAT + c * 4;
            __builtin_nontemporal_store(acc.x * inv, op + 0);
            __builtin_nontemporal_store(acc.y * inv, op + 1);
            __builtin_nontemporal_store(acc.z * inv, op + 2);
            __builtin_nontemporal_store(acc.w * inv, op + 3);
        }
    } else {
        // Safety path for (impossible-here) skewed bins: LDS feature atomics.
        for (int i = t; i < NODES_PER_BIN * D_FEAT; i += 256) u.feat[i] = 0.f;
        __syncthreads();
        for (int i = lo + t; i < hi; i += 256) {
            unsigned int pk = staging[i];
            int dl = (pk >> 16) & (NODES_PER_BIN - 1);
            int s = (int)(pk & 0xFFFFu);
            for (int f = 0; f < D_FEAT; ++f)
                atomicAdd(&u.feat[dl * D_FEAT + f], xs[s * D_FEAT + f]);
        }
        __syncthreads();
        int g = t >> 4, c = t & 15;
        for (int ng = g; ng < NODES_PER_BIN; ng += 16) {
            int node = nodeLo + ng;
            if (node >= N_NODES) break;
            float inv = 1.0f / fmaxf((float)cntL[ng], 1.0f);
            float* op = out + (size_t)node * D_FEAT + c * 4;
            op[0] = u.feat[ng * D_FEAT + c * 4 + 0] * inv;
            op[1] = u.feat[ng * D_FEAT + c * 4 + 1] * inv;
            op[2] = u.feat[ng * D_FEAT + c * 4 + 2] * inv;
            op[3] = u.feat[ng * D_FEAT + c * 4 + 3] * inv;
        }
    }
}

// ---------------- Fallback (small ws): baseline atomic push ----------------

__global__ void scatter_kernel(const float* __restrict__ xs,
                               const int* __restrict__ src,
                               const int* __restrict__ dst,
                               float* __restrict__ sums,
                               float* __restrict__ counts) {
    int tid = blockIdx.x * blockDim.x + threadIdx.x;
    int e = tid >> 4;
    int c = tid & 15;
    if (e >= N_EDGES) return;
    int s = src[e];
    int d = dst[e];
    const float4 v = *reinterpret_cast<const float4*>(xs + (size_t)s * D_FEAT + c * 4);
    float* outp = sums + (size_t)d * D_FEAT + c * 4;
    atomicAdd(outp + 0, v.x);
    atomicAdd(outp + 1, v.y);
    atomicAdd(outp + 2, v.z);
    atomicAdd(outp + 3, v.w);
    if (c == 0) atomicAdd(counts + d, 1.0f);
}

__global__ void divide_kernel(float* __restrict__ out, const float* __restrict__ counts) {
    int tid = blockIdx.x * blockDim.x + threadIdx.x;
    if (tid >= N_NODES * D_FEAT / 4) return;
    int node = tid >> 4;
    float inv = 1.0f / fmaxf(counts[node], 1.0f);
    float4 v = reinterpret_cast<const float4*>(out)[tid];
    v.x *= inv; v.y *= inv; v.z *= inv; v.w *= inv;
    reinterpret_cast<float4*>(out)[tid] = v;
}

// ---------------- launch ----------------

extern "C" void kernel_launch(void* const* d_in, const int* in_sizes, int n_in,
                              void* d_out, int out_size, void* d_ws, size_t ws_size,
                              hipStream_t stream) {
    const float* xs  = (const float*)d_in[0];
    const int*   src = (const int*)d_in[1];
    const int*   dst = (const int*)d_in[2];
    float* out = (float*)d_out;

    size_t need = (size_t)(NCELL + (NCELL + 1) + NCELL + N_EDGES) * sizeof(int);
    if (ws_size < need) {
        float* counts = (float*)d_ws;
        hipMemsetAsync(out, 0, (size_t)N_NODES * D_FEAT * sizeof(float), stream);
        hipMemsetAsync(counts, 0, (size_t)N_NODES * sizeof(float), stream);
        scatter_kernel<<<(N_EDGES * 16 + 255) / 256, 256, 0, stream>>>(xs, src, dst, out, counts);
        divide_kernel<<<(N_NODES * D_FEAT / 4 + 255) / 256, 256, 0, stream>>>(out, counts);
        return;
    }

    int* ws = (int*)d_ws;
    int* hist2    = ws;                       // NCELL
    int* segStart = hist2 + NCELL;            // NCELL + 1
    int* cursor   = segStart + NCELL + 1;     // NCELL
    unsigned int* staging = (unsigned int*)(cursor + NCELL);  // N_EDGES

    hipMemsetAsync(hist2, 0, (size_t)NCELL * sizeof(int), stream);

    binhist_kernel<<<EDGE_BLOCKS, 256, 0, stream>>>(dst, hist2);
    binscan_kernel<<<1, SCAN2_THREADS, 0, stream>>>(hist2, segStart, cursor);
    binscatter_kernel<<<EDGE_BLOCKS, 256, 0, stream>>>(src, dst, cursor, staging);
    binpull_kernel<<<NBINS, 256, 0, stream>>>(xs, staging, segStart, out);
}

// Round 9
// 124.076 us; speedup vs baseline: 2.3116x; 1.4832x over previous
//
#include <hip/hip_runtime.h>

#define N_NODES 50000
#define N_EDGES 800000
#define D_FEAT 64

#define NPART 200                 // edge partitions
#define EPP (N_EDGES / NPART)     // 4000 edges per partition (exact)
#define BIG_SHIFT 9
#define BIG_NODES 512
#define NBIG ((N_NODES + BIG_NODES - 1) / BIG_NODES)  // 98 coarse bins
#define NODES_PER_SUB 64
#define LCAP 4096                 // LDS edge-list capacity per 64-node sub-bin

// ---- K1: per-partition LDS histogram over 98 coarse bins. Zero global atomics.
__global__ __launch_bounds__(1024) void part_hist_kernel(const int* __restrict__ dst,
                                                         int* __restrict__ histBB) {
    __shared__ int h[NBIG];
    int t = threadIdx.x, blk = blockIdx.x;
    if (t < NBIG) h[t] = 0;
    __syncthreads();
    int base = blk * EPP;
    for (int i = t; i < EPP; i += 1024)
        atomicAdd(&h[dst[base + i] >> BIG_SHIFT], 1);
    __syncthreads();
    if (t < NBIG) histBB[blk * NBIG + t] = h[t];   // row-contiguous store
}

// ---- K3: per-bin exclusive scan over the 200 partitions (one block per bin).
__global__ void col_scan_kernel(const int* __restrict__ histBB,
                                int* __restrict__ baseBB,
                                int* __restrict__ binTot) {
    __shared__ int lds[256];
    int bin = blockIdx.x, t = threadIdx.x;
    int v = (t < NPART) ? histBB[t * NBIG + bin] : 0;
    lds[t] = v;
    __syncthreads();
    for (int off = 1; off < 256; off <<= 1) {
        int x = (t >= off) ? lds[t - off] : 0;
        __syncthreads();
        lds[t] += x;
        __syncthreads();
    }
    if (t < NPART) baseBB[t * NBIG + bin] = lds[t] - v;  // exclusive within bin
    if (t == 255) binTot[bin] = lds[255];
}

// ---- K2: exclusive scan of 98 bin totals.
__global__ void bin_scan_kernel(const int* __restrict__ binTot, int* __restrict__ binBase) {
    __shared__ int wsum[2];
    int t = threadIdx.x;                  // 128 threads, 2 waves
    int v = (t < NBIG) ? binTot[t] : 0;
    int lane = t & 63, wave = t >> 6;
    int incl = v;
    #pragma unroll
    for (int o = 1; o < 64; o <<= 1) { int x = __shfl_up(incl, o); if (lane >= o) incl += x; }
    if (lane == 63) wsum[wave] = incl;
    __syncthreads();
    int base = (wave == 1) ? wsum[0] : 0;
    if (t < NBIG) binBase[t] = base + incl - v;
    if (t == NBIG - 1) binBase[NBIG] = base + incl;
}

// ---- K4: re-read edges; LDS cursors seeded with exact global bases; LDS-atomic
// rank; packed store. Runs of ~41 contiguous words per (part,bin) -> good lines.
__global__ __launch_bounds__(1024) void part_scatter_kernel(const int* __restrict__ src,
                                                            const int* __restrict__ dst,
                                                            const int* __restrict__ baseBB,
                                                            const int* __restrict__ binBase,
                                                            unsigned int* __restrict__ staging) {
    __shared__ int cur[NBIG];
    int t = threadIdx.x, blk = blockIdx.x;
    if (t < NBIG) cur[t] = binBase[t] + baseBB[blk * NBIG + t];
    __syncthreads();
    int base = blk * EPP;
    for (int i = t; i < EPP; i += 1024) {
        int d = dst[base + i];
        int bin = d >> BIG_SHIFT;
        int pos = atomicAdd(&cur[bin], 1);           // LDS atomic
        staging[pos] = (unsigned int)src[base + i] |
                       ((unsigned int)(d & (BIG_NODES - 1)) << 16);
    }
}

// ---- K5: per-64-node sub-bin: filter parent segment (hot in L2), LDS counting
// sort, float4 register pull, divide, coalesced nontemporal store.
__global__ __launch_bounds__(256) void binpull_kernel(const float* __restrict__ xs,
                                                      const unsigned int* __restrict__ staging,
                                                      const int* __restrict__ binBase,
                                                      float* __restrict__ out) {
    __shared__ int cntL[NODES_PER_SUB];
    __shared__ union U {
        struct {
            int off[NODES_PER_SUB + 1];
            int cur[NODES_PER_SUB];
            unsigned short list[LCAP];
        } s;
        float feat[NODES_PER_SUB * D_FEAT];  // 16 KB fallback arena
    } u;

    int big = blockIdx.x >> 3;
    unsigned int sub = blockIdx.x & 7;
    int t = threadIdx.x;
    int nodeLo = (big << BIG_SHIFT) + ((int)sub << 6);
    if (nodeLo >= N_NODES) return;       // uniform per block
    int lo = binBase[big], hi = binBase[big + 1];

    if (t < NODES_PER_SUB) cntL[t] = 0;
    __syncthreads();
    for (int i = lo + t; i < hi; i += 256) {
        unsigned int dl = staging[i] >> 16;
        if ((dl >> 6) == sub) atomicAdd(&cntL[dl & 63], 1);
    }
    __syncthreads();
    if (t < 64) {
        int v = cntL[t];
        int incl = v;
        #pragma unroll
        for (int o = 1; o < 64; o <<= 1) { int x = __shfl_up(incl, o); if (t >= o) incl += x; }
        u.s.off[t] = incl - v;
        u.s.cur[t] = incl - v;
        if (t == 63) u.s.off[64] = incl;
    }
    __syncthreads();
    int n = u.s.off[64];

    if (n <= LCAP) {
        for (int i = lo + t; i < hi; i += 256) {
            unsigned int pk = staging[i];
            unsigned int dl = pk >> 16;
            if ((dl >> 6) == sub) {
                int p = atomicAdd(&u.s.cur[dl & 63], 1);
                u.s.list[p] = (unsigned short)(pk & 0xFFFFu);
            }
        }
        __syncthreads();
        int g = t >> 4, c = t & 15;
        for (int ng = g; ng < NODES_PER_SUB; ng += 16) {
            int node = nodeLo + ng;
            if (node >= N_NODES) break;
            int beg = u.s.off[ng], end = u.s.off[ng + 1];
            float4 acc = make_float4(0.f, 0.f, 0.f, 0.f);
            int j = beg;
            for (; j + 4 <= end; j += 4) {
                int s0 = u.s.list[j], s1 = u.s.list[j + 1];
                int s2 = u.s.list[j + 2], s3 = u.s.list[j + 3];
                float4 v0 = *reinterpret_cast<const float4*>(xs + s0 * D_FEAT + c * 4);
                float4 v1 = *reinterpret_cast<const float4*>(xs + s1 * D_FEAT + c * 4);
                float4 v2 = *reinterpret_cast<const float4*>(xs + s2 * D_FEAT + c * 4);
                float4 v3 = *reinterpret_cast<const float4*>(xs + s3 * D_FEAT + c * 4);
                acc.x += v0.x + v1.x + v2.x + v3.x;
                acc.y += v0.y + v1.y + v2.y + v3.y;
                acc.z += v0.z + v1.z + v2.z + v3.z;
                acc.w += v0.w + v1.w + v2.w + v3.w;
            }
            for (; j < end; ++j) {
                int s0 = u.s.list[j];
                float4 v0 = *reinterpret_cast<const float4*>(xs + s0 * D_FEAT + c * 4);
                acc.x += v0.x; acc.y += v0.y; acc.z += v0.z; acc.w += v0.w;
            }
            float inv = 1.0f / fmaxf((float)(end - beg), 1.0f);
            float* op = out + (size_t)node * D_FEAT + c * 4;
            __builtin_nontemporal_store(acc.x * inv, op + 0);
            __builtin_nontemporal_store(acc.y * inv, op + 1);
            __builtin_nontemporal_store(acc.z * inv, op + 2);
            __builtin_nontemporal_store(acc.w * inv, op + 3);
        }
    } else {
        // Safety path (statistically unreachable): LDS feature atomics.
        for (int i = t; i < NODES_PER_SUB * D_FEAT; i += 256) u.feat[i] = 0.f;
        __syncthreads();
        for (int i = lo + t; i < hi; i += 256) {
            unsigned int pk = staging[i];
            unsigned int dl = pk >> 16;
            if ((dl >> 6) == sub) {
                int s = (int)(pk & 0xFFFFu);
                int ln = dl & 63;
                for (int f = 0; f < D_FEAT; ++f)
                    atomicAdd(&u.feat[ln * D_FEAT + f], xs[s * D_FEAT + f]);
            }
        }
        __syncthreads();
        int g = t >> 4, c = t & 15;
        for (int ng = g; ng < NODES_PER_SUB; ng += 16) {
            int node = nodeLo + ng;
            if (node >= N_NODES) break;
            float inv = 1.0f / fmaxf((float)cntL[ng], 1.0f);
            float* op = out + (size_t)node * D_FEAT + c * 4;
            op[0] = u.feat[ng * D_FEAT + c * 4 + 0] * inv;
            op[1] = u.feat[ng * D_FEAT + c * 4 + 1] * inv;
            op[2] = u.feat[ng * D_FEAT + c * 4 + 2] * inv;
            op[3] = u.feat[ng * D_FEAT + c * 4 + 3] * inv;
        }
    }
}

// ---------------- Fallback (small ws): baseline atomic push ----------------

__global__ void scatter_kernel(const float* __restrict__ xs,
                               const int* __restrict__ src,
                               const int* __restrict__ dst,
                               float* __restrict__ sums,
                               float* __restrict__ counts) {
    int tid = blockIdx.x * blockDim.x + threadIdx.x;
    int e = tid >> 4;
    int c = tid & 15;
    if (e >= N_EDGES) return;
    int s = src[e];
    int d = dst[e];
    const float4 v = *reinterpret_cast<const float4*>(xs + (size_t)s * D_FEAT + c * 4);
    float* outp = sums + (size_t)d * D_FEAT + c * 4;
    atomicAdd(outp + 0, v.x);
    atomicAdd(outp + 1, v.y);
    atomicAdd(outp + 2, v.z);
    atomicAdd(outp + 3, v.w);
    if (c == 0) atomicAdd(counts + d, 1.0f);
}

__global__ void divide_kernel(float* __restrict__ out, const float* __restrict__ counts) {
    int tid = blockIdx.x * blockDim.x + threadIdx.x;
    if (tid >= N_NODES * D_FEAT / 4) return;
    int node = tid >> 4;
    float inv = 1.0f / fmaxf(counts[node], 1.0f);
    float4 v = reinterpret_cast<const float4*>(out)[tid];
    v.x *= inv; v.y *= inv; v.z *= inv; v.w *= inv;
    reinterpret_cast<float4*>(out)[tid] = v;
}

// ---------------- launch ----------------

extern "C" void kernel_launch(void* const* d_in, const int* in_sizes, int n_in,
                              void* d_out, int out_size, void* d_ws, size_t ws_size,
                              hipStream_t stream) {
    const float* xs  = (const float*)d_in[0];
    const int*   src = (const int*)d_in[1];
    const int*   dst = (const int*)d_in[2];
    float* out = (float*)d_out;

    size_t need = (size_t)(NPART * NBIG + NPART * NBIG + NBIG + (NBIG + 1) + N_EDGES) * sizeof(int);
    if (ws_size < need) {
        float* counts = (float*)d_ws;
        hipMemsetAsync(out, 0, (size_t)N_NODES * D_FEAT * sizeof(float), stream);
        hipMemsetAsync(counts, 0, (size_t)N_NODES * sizeof(float), stream);
        scatter_kernel<<<(N_EDGES * 16 + 255) / 256, 256, 0, stream>>>(xs, src, dst, out, counts);
        divide_kernel<<<(N_NODES * D_FEAT / 4 + 255) / 256, 256, 0, stream>>>(out, counts);
        return;
    }

    int* ws = (int*)d_ws;
    int* histBB  = ws;                          // NPART*NBIG
    int* baseBB  = histBB + NPART * NBIG;       // NPART*NBIG
    int* binTot  = baseBB + NPART * NBIG;       // NBIG
    int* binBase = binTot + NBIG;               // NBIG+1
    unsigned int* staging = (unsigned int*)(binBase + NBIG + 1);  // N_EDGES

    part_hist_kernel<<<NPART, 1024, 0, stream>>>(dst, histBB);
    col_scan_kernel<<<NBIG, 256, 0, stream>>>(histBB, baseBB, binTot);
    bin_scan_kernel<<<1, 128, 0, stream>>>(binTot, binBase);
    part_scatter_kernel<<<NPART, 1024, 0, stream>>>(src, dst, baseBB, binBase, staging);
    binpull_kernel<<<NBIG * 8, 256, 0, stream>>>(xs, staging, binBase, out);
}